// Round 3
// baseline (1498.255 us; speedup 1.0000x reference)
//
#include <hip/hip_runtime.h>
#include <hip/hip_cooperative_groups.h>
#include <math.h>

namespace cg = cooperative_groups;

// Sinkhorn [B=32, N=1024, N=1024] fp32, TAU=1, 10 iters.
// Identity: log_s == s + r[b,i] + c[b,j] at every step.
//   even: r = -LSE_j(s + c);  odd: c = -LSE_i(s + r);  out = exp(s + r + c).
// Single persistent cooperative kernel: 10 half-sweeps + finalize, grid.sync
// between phases. s (128 MB) stays L3-resident across sweeps.

#define BATCH 32
#define N 1024
#define NBLOCKS 1024   // = BATCH * 32 chunks; 4 blocks/CU co-resident
#define NTHREADS 256

__global__ __launch_bounds__(256, 4) void sinkhorn_persistent(
    const float* __restrict__ s, float* __restrict__ r, float* __restrict__ c,
    float* __restrict__ out)
{
    cg::grid_group grid = cg::this_grid();
    const int t     = threadIdx.x;
    const int b     = blockIdx.x >> 5;   // batch
    const int chunk = blockIdx.x & 31;   // 32-row / 32-col chunk within batch

    __shared__ float cs[N];          // staged c[b,:] (row phase, finalize)
    __shared__ float rs[N];          // staged r[b,:] (col phase)
    __shared__ float4 sm[32][8];     // col-phase partial maxes
    __shared__ float4 sl[32][8];     // col-phase partial sums

    const int wave = t >> 6;
    const int lane = t & 63;

    for (int it = 0; it < 10; it += 2) {
        // ---- row phase: r[b, chunk*32+row] = -LSE_j(s[b,row,:] + c[b,:]) ----
        if (it == 0)
            ((float4*)cs)[t] = make_float4(0.f, 0.f, 0.f, 0.f);
        else
            ((float4*)cs)[t] = ((const float4*)(c + b * N))[t];
        __syncthreads();
        const float4* cs4 = (const float4*)cs;
        for (int rp = 0; rp < 8; rp++) {                 // 4 waves x 8 rows
            const int row = wave * 8 + rp;               // 0..31
            const float4* srow =
                (const float4*)(s + ((size_t)(b * N + chunk * 32 + row)) * N);
            float x[16];
#pragma unroll
            for (int k = 0; k < 4; k++) {
                float4 v  = srow[lane + 64 * k];
                float4 cv = cs4[lane + 64 * k];
                x[4*k+0] = v.x + cv.x; x[4*k+1] = v.y + cv.y;
                x[4*k+2] = v.z + cv.z; x[4*k+3] = v.w + cv.w;
            }
            float m = x[0];
#pragma unroll
            for (int q = 1; q < 16; q++) m = fmaxf(m, x[q]);
#pragma unroll
            for (int off = 32; off; off >>= 1) m = fmaxf(m, __shfl_xor(m, off, 64));
            float sum = 0.f;
#pragma unroll
            for (int q = 0; q < 16; q++) sum += __expf(x[q] - m);
#pragma unroll
            for (int off = 32; off; off >>= 1) sum += __shfl_xor(sum, off, 64);
            if (lane == 0)
                r[b * N + chunk * 32 + row] = -(m + __logf(sum));
        }
        grid.sync();

        // ---- col phase: c[b, chunk*32+cc] = -LSE_i(s[b,:,cc] + r[b,:]) ----
        ((float4*)rs)[t] = ((const float4*)(r + b * N))[t];
        __syncthreads();
        const int col4 = t & 7;     // float4 within the 32-col chunk
        const int rch  = t >> 3;    // 0..31, each covering 32 rows
        const float4* base =
            (const float4*)(s + ((size_t)(b * N + rch * 32)) * N) + chunk * 8 + col4;
        float4 m4 = make_float4(-3e38f, -3e38f, -3e38f, -3e38f);
        float4 l4 = make_float4(0.f, 0.f, 0.f, 0.f);
#pragma unroll 4
        for (int i = 0; i < 32; i++) {
            float ri = rs[rch * 32 + i];
            float4 v = base[(size_t)i * 256];
            float x0 = v.x + ri, x1 = v.y + ri, x2 = v.z + ri, x3 = v.w + ri;
            float n;
            n = fmaxf(m4.x, x0); l4.x = l4.x * __expf(m4.x - n) + __expf(x0 - n); m4.x = n;
            n = fmaxf(m4.y, x1); l4.y = l4.y * __expf(m4.y - n) + __expf(x1 - n); m4.y = n;
            n = fmaxf(m4.z, x2); l4.z = l4.z * __expf(m4.z - n) + __expf(x2 - n); m4.z = n;
            n = fmaxf(m4.w, x3); l4.w = l4.w * __expf(m4.w - n) + __expf(x3 - n); m4.w = n;
        }
        sm[rch][col4] = m4;
        sl[rch][col4] = l4;
        __syncthreads();
        if (t < 8) {
            float4 M = sm[0][t], L = sl[0][t];
#pragma unroll
            for (int k2 = 1; k2 < 32; k2++) {
                float4 m2 = sm[k2][t], l2 = sl[k2][t];
                float n;
                n = fmaxf(M.x, m2.x); L.x = L.x * __expf(M.x - n) + l2.x * __expf(m2.x - n); M.x = n;
                n = fmaxf(M.y, m2.y); L.y = L.y * __expf(M.y - n) + l2.y * __expf(m2.y - n); M.y = n;
                n = fmaxf(M.z, m2.z); L.z = L.z * __expf(M.z - n) + l2.z * __expf(m2.z - n); M.z = n;
                n = fmaxf(M.w, m2.w); L.w = L.w * __expf(M.w - n) + l2.w * __expf(m2.w - n); M.w = n;
            }
            float4 o;
            o.x = -(M.x + __logf(L.x));
            o.y = -(M.y + __logf(L.y));
            o.z = -(M.z + __logf(L.z));
            o.w = -(M.w + __logf(L.w));
            ((float4*)(c + b * N + chunk * 32))[t] = o;
        }
        grid.sync();
    }

    // ---- finalize: out = exp(s + r + c); block owns (b, 32 rows) ----
    ((float4*)cs)[t] = ((const float4*)(c + b * N))[t];
    if (t < 32) rs[t] = r[b * N + chunk * 32 + t];
    __syncthreads();
    const float4* tile  = (const float4*)(s   + ((size_t)(b * N + chunk * 32)) * N);
    float4*       otile = (float4*)      (out + ((size_t)(b * N + chunk * 32)) * N);
    const float4 cc = ((const float4*)cs)[t];
    for (int j = 0; j < 32; j++) {
        float rr = rs[j];
        float4 v = tile[j * 256 + t];
        float4 o;
        o.x = __expf(v.x + rr + cc.x);
        o.y = __expf(v.y + rr + cc.y);
        o.z = __expf(v.z + rr + cc.z);
        o.w = __expf(v.w + rr + cc.w);
        otile[j * 256 + t] = o;
    }
}

// ---------- fallback path (if cooperative launch fails) ----------
__global__ __launch_bounds__(256) void zero_c_kernel(float* __restrict__ c) {
    c[blockIdx.x * 256 + threadIdx.x] = 0.0f;
}

__global__ __launch_bounds__(256) void row_lse_kernel(const float* __restrict__ s,
                                                      const float* __restrict__ c,
                                                      float* __restrict__ r) {
    const int wave = threadIdx.x >> 6;
    const int lane = threadIdx.x & 63;
    const int row  = blockIdx.x * 4 + wave;
    const int b    = row >> 10;
    const float4* srow = (const float4*)(s + (size_t)row * N);
    const float4* crow = (const float4*)(c + (size_t)b * N);
    float x[16];
#pragma unroll
    for (int k = 0; k < 4; k++) {
        float4 v = srow[lane + k * 64];
        float4 cv = crow[lane + k * 64];
        x[4*k+0]=v.x+cv.x; x[4*k+1]=v.y+cv.y; x[4*k+2]=v.z+cv.z; x[4*k+3]=v.w+cv.w;
    }
    float m = x[0];
#pragma unroll
    for (int q = 1; q < 16; q++) m = fmaxf(m, x[q]);
#pragma unroll
    for (int off = 32; off; off >>= 1) m = fmaxf(m, __shfl_xor(m, off, 64));
    float sum = 0.f;
#pragma unroll
    for (int q = 0; q < 16; q++) sum += __expf(x[q] - m);
#pragma unroll
    for (int off = 32; off; off >>= 1) sum += __shfl_xor(sum, off, 64);
    if (lane == 0) r[row] = -(m + __logf(sum));
}

__global__ __launch_bounds__(1024) void col_lse_direct_kernel(const float* __restrict__ s,
                                                              const float* __restrict__ r,
                                                              float* __restrict__ c) {
    const int b = blockIdx.x;
    const int j = threadIdx.x;
    const float* rb = r + b * N;
    const float* base = s + (size_t)b * N * N + j;
    float m = -3.0e38f, l = 0.f;
    for (int i = 0; i < N; i++) {
        float x  = base[(size_t)i * N] + rb[i];
        float mn = fmaxf(m, x);
        l = l * __expf(m - mn) + __expf(x - mn);
        m = mn;
    }
    c[b * N + j] = -(m + __logf(l));
}

__global__ __launch_bounds__(256) void finalize_kernel(const float* __restrict__ s,
                                                       const float* __restrict__ r,
                                                       const float* __restrict__ c,
                                                       float* __restrict__ out) {
    const int f4  = blockIdx.x * 256 + threadIdx.x;
    const int j4  = f4 & 255;
    const int row = f4 >> 8;
    const int b   = row >> 10;
    float4 v  = ((const float4*)s)[f4];
    float  rr = r[row];
    float4 cc = ((const float4*)c)[(b << 8) + j4];
    float4 o;
    o.x = __expf(v.x + rr + cc.x);
    o.y = __expf(v.y + rr + cc.y);
    o.z = __expf(v.z + rr + cc.z);
    o.w = __expf(v.w + rr + cc.w);
    ((float4*)out)[f4] = o;
}
// ---------- end fallback ----------

extern "C" void kernel_launch(void* const* d_in, const int* in_sizes, int n_in,
                              void* d_out, int out_size, void* d_ws, size_t ws_size,
                              hipStream_t stream) {
    const float* s = (const float*)d_in[0];
    float* out = (float*)d_out;
    float* c = (float*)d_ws;         // BATCH*N floats
    float* r = c + BATCH * N;        // BATCH*N floats

    void* args[] = { (void*)&s, (void*)&r, (void*)&c, (void*)&out };
    hipError_t err = hipLaunchCooperativeKernel(
        (void*)sinkhorn_persistent, dim3(NBLOCKS), dim3(NTHREADS), args, 0, stream);

    if (err != hipSuccess) {
        // Fallback: multi-kernel path.
        zero_c_kernel<<<(BATCH * N) / 256, 256, 0, stream>>>(c);
        for (int it = 0; it < 10; it++) {
            if ((it & 1) == 0)
                row_lse_kernel<<<(BATCH * N) / 4, 256, 0, stream>>>(s, c, r);
            else
                col_lse_direct_kernel<<<BATCH, 1024, 0, stream>>>(s, r, c);
        }
        const int total_f4 = BATCH * N * N / 4;
        finalize_kernel<<<total_f4 / 256, 256, 0, stream>>>(s, r, c, out);
    }
}